// Round 5
// baseline (5130.259 us; speedup 1.0000x reference)
//
#include <hip/hip_runtime.h>

// ---------------------------------------------------------------------------
// 2-layer LSTM (B=64, T=256, D=512, H1=H2=1024) + dense head.
// R12: h-stage through L2 (cached loads) + per-step buffer_inv sc1.
// R11 (1382us lstm): A-reuse pairing confirmed (-172us, conflicts halved).
// Step 5.40us = stage ~2.5 (dominant) + compute ~1.2 + fold/epi ~0.3 +
// barrier ~1.05. Stage = 24 MB/step sc1 h-reads bypassing L2: 64x broadcast
// redundancy served entirely by MALL (~10 TB/s observed). Fix: h loads are
// now PLAIN CACHED; each XCD's L2 fetches each h line once (MSHR-merged)
// and serves its 32 blocks -> MALL traffic 24 MB -> ~2.6 MB/step. Staleness:
// h stores remain sc1 (write-through, drained pre-barrier = R5 publish);
// post-barrier every block issues buffer_inv sc1 + vmcnt(0) BEFORE any h
// load. R6 tried this and lost ONLY because weights then lived in L2 and
// were evicted every step; weights are now AGPR-resident (VGPR=104 proves
// it), so the eviction cost is gone. Dense kernel is safe via the HSA
// dispatch acquire fence. Everything else byte-identical to R11.
// ---------------------------------------------------------------------------

typedef __bf16 bf16x8 __attribute__((ext_vector_type(8)));
typedef float f32x4 __attribute__((ext_vector_type(4)));
typedef unsigned int u32x4 __attribute__((ext_vector_type(4)));
typedef unsigned short u16;

#define LDS_Z_OFF 131584   // Alds worst: 32*(2048+8)*2 = 131584 B
#define LDS_TOTAL 148992   // + Zlds 2*32*68*4 = 17408 B

__device__ __forceinline__ u16 f2bf(float f) {
  unsigned u = __float_as_uint(f);
  unsigned r = (u + 0x7FFFu + ((u >> 16) & 1u)) >> 16;  // RNE (finite inputs)
  return (u16)r;
}

// in: fp32 [R][C] row-major  ->  out: bf16 [C][R] row-major (i.e. B^T layout)
__global__ __launch_bounds__(256) void transpose_to_bf16(
    const float* __restrict__ in, u16* __restrict__ out, int R, int C) {
  __shared__ float tile[32][33];
  int tx = threadIdx.x & 31, ty = threadIdx.x >> 5;  // 32 x 8
  int c0 = blockIdx.x * 32, r0 = blockIdx.y * 32;
#pragma unroll
  for (int i = 0; i < 4; ++i)
    tile[ty + i * 8][tx] = in[(size_t)(r0 + ty + i * 8) * C + (c0 + tx)];
  __syncthreads();
#pragma unroll
  for (int i = 0; i < 4; ++i)
    out[(size_t)(c0 + ty + i * 8) * R + (r0 + tx)] = f2bf(tile[tx][ty + i * 8]);
}

__global__ __launch_bounds__(256) void convert_to_bf16(
    const float* __restrict__ in, u16* __restrict__ out, int n4) {
  int i = blockIdx.x * 256 + threadIdx.x;
  if (i >= n4) return;
  float4 v = reinterpret_cast<const float4*>(in)[i];
  ushort4 o;
  o.x = f2bf(v.x); o.y = f2bf(v.y); o.z = f2bf(v.z); o.w = f2bf(v.w);
  reinterpret_cast<ushort4*>(out)[i] = o;
}

__global__ void init_bar(unsigned* __restrict__ bar) { bar[threadIdx.x] = 0u; }

__device__ __forceinline__ void store_h_sc1(u16* p, unsigned v) {
  asm volatile("global_store_short %0, %1, off sc1" :: "v"(p), "v"(v) : "memory");
}

// Acquire for this step's h data: invalidate L1+L2 copies so cached loads
// see the MALL-fresh values published at the last grid barrier.
__device__ __forceinline__ void cache_inv() {
  asm volatile("buffer_inv sc1\n\ts_waitcnt vmcnt(0)" ::: "memory");
}

// ---- A-staging: cached loads -> LDS via depth-8 ring, manual vmcnt -------
// Chunk = 32 rows x 256 B (one 16B slice per thread, 512 threads).
template <int I, int C0, int DEPTH>
__device__ __forceinline__ void stg_issue(u32x4 (&ring)[DEPTH],
    const u16* b0, const u16* b1) {
  constexpr int OFF = (I < C0 ? I : I - C0) * 256;
  if constexpr (I < C0)
    asm volatile("global_load_dwordx4 %0, %1, off offset:%2"
                 : "=v"(ring[I % DEPTH]) : "v"(b0), "i"(OFF));
  else
    asm volatile("global_load_dwordx4 %0, %1, off offset:%2"
                 : "=v"(ring[I % DEPTH]) : "v"(b1), "i"(OFF));
}

template <int I, int NPRE, int C0, int DEPTH>
__device__ __forceinline__ void stg_pre(u32x4 (&ring)[DEPTH],
    const u16* b0, const u16* b1) {
  if constexpr (I < NPRE) {
    stg_issue<I, C0, DEPTH>(ring, b0, b1);
    stg_pre<I + 1, NPRE, C0, DEPTH>(ring, b0, b1);
  }
}

template <int I, int NC, int C0, int DEPTH>
__device__ __forceinline__ void stg_main(u32x4 (&ring)[DEPTH],
    const u16* b0, const u16* b1, u16* lrow) {
  if constexpr (I < NC) {
    constexpr int ISSUED = (I + DEPTH < NC) ? I + DEPTH : NC;
    constexpr int WAIT = ISSUED - I - 1;
    asm volatile("s_waitcnt vmcnt(%1)" : "+v"(ring[I % DEPTH]) : "i"(WAIT));
    *(u32x4*)(lrow + I * 128) = ring[I % DEPTH];   // ds_write_b128
    if constexpr (I + DEPTH < NC)
      stg_issue<I + DEPTH, C0, DEPTH>(ring, b0, b1);
    stg_main<I + 1, NC, C0, DEPTH>(ring, b0, b1, lrow);
  }
}

template <int NC, int C0>
__device__ __forceinline__ void stage(const u16* b0, const u16* b1, u16* lrow) {
  u32x4 ring[8];
  stg_pre<0, (NC < 8 ? NC : 8), C0, 8>(ring, b0, b1);
  stg_main<0, NC, C0, 8>(ring, b0, b1, lrow);
}

// Fence-free tree barrier (R5-proven). bar lines 128B apart: [0]=root,
// [32*(1+g)]=group ctr, [32*(9+g)]=epoch. Monotone counters, no resets.
__device__ __forceinline__ void grid_barrier(unsigned* __restrict__ bar,
                                             int g, unsigned want) {
  asm volatile("s_waitcnt vmcnt(0)" ::: "memory");  // h stores acked at MALL
  __syncthreads();
  if (threadIdx.x == 0) {
    unsigned old = __hip_atomic_fetch_add(bar + 32 * (1 + g), 1u,
                                          __ATOMIC_RELAXED, __HIP_MEMORY_SCOPE_AGENT);
    if (old == 32u * want - 1u) {
      unsigned r = __hip_atomic_fetch_add(bar, 1u, __ATOMIC_RELAXED,
                                          __HIP_MEMORY_SCOPE_AGENT);
      if (r == 8u * want - 1u) {
#pragma unroll
        for (int i = 0; i < 8; ++i)
          __hip_atomic_store(bar + 32 * (9 + i), want, __ATOMIC_RELAXED,
                             __HIP_MEMORY_SCOPE_AGENT);
      }
    }
    while (__hip_atomic_load(bar + 32 * (9 + g), __ATOMIC_RELAXED,
                             __HIP_MEMORY_SCOPE_AGENT) < want)
      __builtin_amdgcn_s_sleep(1);
  }
  __syncthreads();
}

// One layer's persistent loop. Stage chunk = 256 B/row: NC = row_bytes/256.
// MFMA k-chunks NCH = NC*4; wave (cp, kq) = (gate-pair, K-quarter) holds
// breg[2][NC] (gates 2cp,2cp+1; k-chunks kq*NC..kq*NC+NC-1). Each a0/a1
// ds_read feeds 2 MFMAs. kq-partials: pairwise fold into Zlds[2] buffers.
template <int NC, int C0, bool IS2>
__device__ __forceinline__ void run_layer(
    const u16* __restrict__ xbf, const u16* __restrict__ Wt,
    const u16* __restrict__ Ut, const float* __restrict__ bias,
    u16* __restrict__ h1r, u16* __restrict__ h2r, unsigned* __restrict__ bar,
    int strip, int mhalf, char* smem, int g) {
  constexpr int KE = NC * 128;   // K (elements)
  constexpr int P = KE + 8;      // LDS row pitch (elements); +16B bank stagger
  constexpr int WCH = C0 * 4;    // MFMA k-chunks in W segment
  u16* Alds = (u16*)smem;                       // [32][P]
  float* Zlds = (float*)(smem + LDS_Z_OFF);     // [2][32][68]
  const int tid = threadIdx.x;
  const int wave = tid >> 6, lane = tid & 63;
  const int cp = wave & 1, kq = wave >> 1;      // gate-pair, K-quarter
  const int quad = lane >> 4, l16 = lane & 15;

  // ---- weights -> registers (once; breg[2][NC] -> AGPR-resident) ----
  bf16x8 breg[2][NC];
#pragma unroll
  for (int gi = 0; gi < 2; ++gi) {
    const int col = (2 * cp + gi) * 1024 + strip * 16 + l16;
#pragma unroll
    for (int j = 0; j < NC; ++j) {
      const int ks = kq * NC + j;
      breg[gi][j] = (ks < WCH)
        ? *(const bf16x8*)(Wt + (size_t)col * (C0 * 128) + ks * 32 + quad * 8)
        : *(const bf16x8*)(Ut + (size_t)col * 1024 + (ks - WCH) * 32 + quad * 8);
    }
  }

  // ---- epilogue coords: thread owns one (batch em, unit eu) ----
  const int eu = tid & 15, em = tid >> 4;       // em 0..31
  const float bz0 = bias[strip * 16 + eu];
  const float bz1 = bias[1024 + strip * 16 + eu];
  const float bz2 = bias[2048 + strip * 16 + eu];
  const float bz3 = bias[3072 + strip * 16 + eu];
  float c = 0.f;

  // ---- staging coords: thread stages row sr, 16B slice l8 (16/row) ----
  const int sr = tid >> 4, l8 = tid & 15;
  const int sb = mhalf * 32 + sr;               // global batch row
  u16* lrow = Alds + sr * P + l8 * 8;

  const u16* a0p = Alds + l16 * P + quad * 8 + kq * (NC * 32);
  const u16* a1p = a0p + 16 * P;

  // Z columns this wave produces: gates 2cp (+0) and 2cp+1 (+16)
  const int zc0 = cp * 32 + l16, zc1 = zc0 + 16;
  float* zb = Zlds + (kq & 1) * (32 * 68);

  for (int s = 0; s <= 256; ++s) {
    const int t = IS2 ? (s - 1) : s;
    if (t >= 0 && t < 256) {
      const u16 *b0, *b1;
      if constexpr (IS2) {
        b0 = h1r + (size_t)(t & 1) * 65536 + (size_t)sb * 1024 + l8 * 8;
        b1 = h2r + (size_t)((t - 1) & 1) * 65536 + (size_t)sb * 1024 + l8 * 8;
      } else {
        b0 = xbf + ((size_t)sb * 256 + t) * 512 + l8 * 8;
        b1 = h1r + (size_t)((t - 1) & 1) * 65536 + (size_t)sb * 1024 + l8 * 8;
      }
      // Acquire: drop stale L1/L2 h lines (published at last grid barrier).
      cache_inv();
      if (t > 0) {
        stage<NC, C0>(b0, b1, lrow);
      } else {                       // first step: recurrent state is zero
        stage<C0, C0>(b0, b0, lrow);
#pragma unroll
        for (int i = C0; i < NC; ++i)
          *(u32x4*)(lrow + i * 128) = (u32x4){0u, 0u, 0u, 0u};
      }
      __syncthreads();

      // acc[gi][mh]: gi = gate-in-pair, mh = m-half (rows mh*16..mh*16+15)
      f32x4 acc00 = {0.f, 0.f, 0.f, 0.f}, acc10 = {0.f, 0.f, 0.f, 0.f};
      f32x4 acc01 = {0.f, 0.f, 0.f, 0.f}, acc11 = {0.f, 0.f, 0.f, 0.f};
#pragma unroll
      for (int j = 0; j < NC; ++j) {
        bf16x8 a0 = *(const bf16x8*)(a0p + j * 32);
        bf16x8 a1 = *(const bf16x8*)(a1p + j * 32);
        acc00 = __builtin_amdgcn_mfma_f32_16x16x32_bf16(a0, breg[0][j], acc00, 0, 0, 0);
        acc10 = __builtin_amdgcn_mfma_f32_16x16x32_bf16(a1, breg[0][j], acc10, 0, 0, 0);
        acc01 = __builtin_amdgcn_mfma_f32_16x16x32_bf16(a0, breg[1][j], acc01, 0, 0, 0);
        acc11 = __builtin_amdgcn_mfma_f32_16x16x32_bf16(a1, breg[1][j], acc11, 0, 0, 0);
      }

      // kq-partial fold: kq<2 store into buffer (kq&1); sync; kq>=2 add into
      // same buffer; sync. C/D layout: col=lane&15 (unit), row=quad*4+i.
      if (kq < 2) {
#pragma unroll
        for (int i = 0; i < 4; ++i) {
          zb[(quad * 4 + i) * 68 + zc0] = acc00[i];
          zb[(16 + quad * 4 + i) * 68 + zc0] = acc10[i];
          zb[(quad * 4 + i) * 68 + zc1] = acc01[i];
          zb[(16 + quad * 4 + i) * 68 + zc1] = acc11[i];
        }
      }
      __syncthreads();
      if (kq >= 2) {
#pragma unroll
        for (int i = 0; i < 4; ++i) {
          zb[(quad * 4 + i) * 68 + zc0] += acc00[i];
          zb[(16 + quad * 4 + i) * 68 + zc0] += acc10[i];
          zb[(quad * 4 + i) * 68 + zc1] += acc01[i];
          zb[(16 + quad * 4 + i) * 68 + zc1] += acc11[i];
        }
      }
      __syncthreads();

      u16* hring = IS2 ? h2r : h1r;
      u16* hp = hring + (size_t)(t & 1) * 65536 +
                (size_t)(mhalf * 32 + em) * 1024 + strip * 16 + eu;
      {
        float zi = Zlds[em * 68 + eu]      + Zlds[(32 + em) * 68 + eu]      + bz0;
        float zf = Zlds[em * 68 + 16 + eu] + Zlds[(32 + em) * 68 + 16 + eu] + bz1;
        float zg = Zlds[em * 68 + 32 + eu] + Zlds[(32 + em) * 68 + 32 + eu] + bz2;
        float zo = Zlds[em * 68 + 48 + eu] + Zlds[(32 + em) * 68 + 48 + eu] + bz3;
        float ig = 1.f / (1.f + __expf(-zi));
        float fg = 1.f / (1.f + __expf(-zf));
        float gg = 1.f - 2.f / (1.f + __expf(2.f * zg));
        float og = 1.f / (1.f + __expf(-zo));
        c = fg * c + ig * gg;
        float h = og * (1.f - 2.f / (1.f + __expf(2.f * c)));
        store_h_sc1(hp, (unsigned)f2bf(h));
      }
    }
    if (s < 256) grid_barrier(bar, g, (unsigned)(s + 1));
  }
}

__global__ __launch_bounds__(512, 2) void lstm_persistent(
    const u16* __restrict__ xbf,   // [64][256][512] bf16
    const u16* __restrict__ W1t,   // [4096][512]
    const u16* __restrict__ U1t,   // [4096][1024]
    const float* __restrict__ b1,
    const u16* __restrict__ W2t,   // [4096][1024]
    const u16* __restrict__ U2t,   // [4096][1024]
    const float* __restrict__ b2,
    u16* __restrict__ h1r,         // [2][64][1024] bf16
    u16* __restrict__ h2r,         // [2][64][1024] bf16
    unsigned* __restrict__ bar) {
  extern __shared__ __align__(16) char smem[];
  const int blk = blockIdx.x;
  const bool is2 = blk >= 128;
  const int lb = is2 ? blk - 128 : blk;
  const int strip = lb >> 1;       // 64 col-strips of 16 units
  const int mhalf = lb & 1;        // batch half
  const int g = blk & 7;
  if (!is2)
    run_layer<12, 4, false>(xbf, W1t, U1t, b1, h1r, h2r, bar,
                            strip, mhalf, smem, g);
  else
    run_layer<16, 8, true>(xbf, W2t, U2t, b2, h1r, h2r, bar,
                           strip, mhalf, smem, g);
}

// out[64][512] = h2_last @ Wd + bd.  One wave per 16x16 tile, K=1024.
__global__ __launch_bounds__(64) void dense_kernel(
    const u16* __restrict__ h2,    // [64][1024] bf16
    const u16* __restrict__ Wdt,   // [512][1024] bf16
    const float* __restrict__ bd,
    float* __restrict__ out) {
  int mt = blockIdx.x >> 5;  // 0..3
  int nt = blockIdx.x & 31;  // 0..31
  int lane = threadIdx.x;
  int quad = lane >> 4, l16 = lane & 15;
  f32x4 acc = {0.f, 0.f, 0.f, 0.f};
  const u16* ap = h2 + (size_t)(mt * 16 + l16) * 1024 + quad * 8;
  const u16* bp = Wdt + (size_t)(nt * 16 + l16) * 1024 + quad * 8;
#pragma unroll
  for (int ks = 0; ks < 32; ++ks) {
    bf16x8 a = *reinterpret_cast<const bf16x8*>(ap + ks * 32);
    bf16x8 b = *reinterpret_cast<const bf16x8*>(bp + ks * 32);
    acc = __builtin_amdgcn_mfma_f32_16x16x32_bf16(a, b, acc, 0, 0, 0);
  }
  int colo = nt * 16 + l16;
  float bias = bd[colo];
#pragma unroll
  for (int i = 0; i < 4; ++i)
    out[(size_t)(mt * 16 + quad * 4 + i) * 512 + colo] = acc[i] + bias;
}

extern "C" void kernel_launch(void* const* d_in, const int* in_sizes, int n_in,
                              void* d_out, int out_size, void* d_ws, size_t ws_size,
                              hipStream_t stream) {
  const float* x  = (const float*)d_in[0];
  const float* W1 = (const float*)d_in[1];
  const float* U1 = (const float*)d_in[2];
  const float* b1 = (const float*)d_in[3];
  const float* W2 = (const float*)d_in[4];
  const float* U2 = (const float*)d_in[5];
  const float* b2 = (const float*)d_in[6];
  const float* Wd = (const float*)d_in[7];
  const float* bd = (const float*)d_in[8];
  float* out = (float*)d_out;

  char* p = (char*)d_ws;
  auto carve = [&](size_t bytes) -> char* {
    char* r = p;
    p += (bytes + 255) & ~(size_t)255;
    return r;
  };
  // ~45.5 MiB total (R2-proven budget; R1's 78 MiB overflowed ws)
  u16* W1t = (u16*)carve((size_t)4096 * 512 * 2);
  u16* U1t = (u16*)carve((size_t)4096 * 1024 * 2);
  u16* W2t = (u16*)carve((size_t)4096 * 1024 * 2);
  u16* U2t = (u16*)carve((size_t)4096 * 1024 * 2);
  u16* Wdt = (u16*)carve((size_t)512 * 1024 * 2);
  u16* xbf = (u16*)carve((size_t)64 * 256 * 512 * 2);
  u16* h1r = (u16*)carve((size_t)2 * 64 * 1024 * 2);
  u16* h2r = (u16*)carve((size_t)2 * 64 * 1024 * 2);
  unsigned* bar = (unsigned*)carve(1024 * 4);
  (void)ws_size; (void)in_sizes; (void)n_in; (void)out_size;

  transpose_to_bf16<<<dim3(128, 16), 256, 0, stream>>>(W1, W1t, 512, 4096);
  transpose_to_bf16<<<dim3(128, 32), 256, 0, stream>>>(U1, U1t, 1024, 4096);
  transpose_to_bf16<<<dim3(128, 32), 256, 0, stream>>>(W2, W2t, 1024, 4096);
  transpose_to_bf16<<<dim3(128, 32), 256, 0, stream>>>(U2, U2t, 1024, 4096);
  transpose_to_bf16<<<dim3(16, 32), 256, 0, stream>>>(Wd, Wdt, 1024, 512);
  convert_to_bf16<<<8192, 256, 0, stream>>>(x, xbf, 64 * 256 * 512 / 4);
  init_bar<<<1, 1024, 0, stream>>>(bar);

  hipFuncSetAttribute(reinterpret_cast<const void*>(lstm_persistent),
                      hipFuncAttributeMaxDynamicSharedMemorySize, LDS_TOTAL);
  lstm_persistent<<<256, 512, LDS_TOTAL, stream>>>(
      xbf, W1t, U1t, b1, W2t, U2t, b2, h1r, h2r, bar);

  dense_kernel<<<128, 64, 0, stream>>>(h2r + 65536, Wdt, bd, out);
}

// Round 6
// 1498.478 us; speedup vs baseline: 3.4236x; 3.4236x over previous
//
#include <hip/hip_runtime.h>

// ---------------------------------------------------------------------------
// 2-layer LSTM (B=64, T=256, D=512, H1=H2=1024) + dense head.
// R13: R11 + XOR bank-swizzle on the A-tile (T2). R12 (buffer_inv, 5075us):
// whole-L2 invalidate per step is unaffordable -> reverted; sc1/MALL is the
// only coherent h path. R11 counters: 6.7e7 bank-conflict cy = ~1020 extra
// cy/CU/step (~33% over the ~3070cy conflict-free b128 floor of the 256KB
// A-read). Fix: pitch P=K (rows 128B-aligned) + byte_off ^= (row&7)<<4 on
// BOTH ds_write (staging, per-lane addrs -> swizzle legal) and ds_read
// (fragment loads; XOR applied to the full logical offset per access, so no
// carry-through-base bug). 16 lanes -> 8 distinct 16B slots x2 = full LDS BW.
// Everything else byte-identical to R11 (sc1 staging, pairing, fold, barrier).
// ---------------------------------------------------------------------------

typedef __bf16 bf16x8 __attribute__((ext_vector_type(8)));
typedef float f32x4 __attribute__((ext_vector_type(4)));
typedef unsigned int u32x4 __attribute__((ext_vector_type(4)));
typedef unsigned short u16;

#define LDS_Z_OFF 131584   // Alds worst: 32*2048*2 = 131072 B (P=K now)
#define LDS_TOTAL 148992   // + Zlds 2*32*68*4 = 17408 B

__device__ __forceinline__ u16 f2bf(float f) {
  unsigned u = __float_as_uint(f);
  unsigned r = (u + 0x7FFFu + ((u >> 16) & 1u)) >> 16;  // RNE (finite inputs)
  return (u16)r;
}

// in: fp32 [R][C] row-major  ->  out: bf16 [C][R] row-major (i.e. B^T layout)
__global__ __launch_bounds__(256) void transpose_to_bf16(
    const float* __restrict__ in, u16* __restrict__ out, int R, int C) {
  __shared__ float tile[32][33];
  int tx = threadIdx.x & 31, ty = threadIdx.x >> 5;  // 32 x 8
  int c0 = blockIdx.x * 32, r0 = blockIdx.y * 32;
#pragma unroll
  for (int i = 0; i < 4; ++i)
    tile[ty + i * 8][tx] = in[(size_t)(r0 + ty + i * 8) * C + (c0 + tx)];
  __syncthreads();
#pragma unroll
  for (int i = 0; i < 4; ++i)
    out[(size_t)(c0 + ty + i * 8) * R + (r0 + tx)] = f2bf(tile[tx][ty + i * 8]);
}

__global__ __launch_bounds__(256) void convert_to_bf16(
    const float* __restrict__ in, u16* __restrict__ out, int n4) {
  int i = blockIdx.x * 256 + threadIdx.x;
  if (i >= n4) return;
  float4 v = reinterpret_cast<const float4*>(in)[i];
  ushort4 o;
  o.x = f2bf(v.x); o.y = f2bf(v.y); o.z = f2bf(v.z); o.w = f2bf(v.w);
  reinterpret_cast<ushort4*>(out)[i] = o;
}

__global__ void init_bar(unsigned* __restrict__ bar) { bar[threadIdx.x] = 0u; }

__device__ __forceinline__ void store_h_sc1(u16* p, unsigned v) {
  asm volatile("global_store_short %0, %1, off sc1" :: "v"(p), "v"(v) : "memory");
}

// ---- A-staging: sc1/cached loads -> LDS via depth-8 ring, manual vmcnt ----
// Chunk = 32 rows x 256 B (one 16B slice per thread, 512 threads).
template <int I, int C0, int DEPTH, bool SC0, bool SC1>
__device__ __forceinline__ void stg_issue(u32x4 (&ring)[DEPTH],
    const u16* b0, const u16* b1) {
  constexpr int OFF = (I < C0 ? I : I - C0) * 256;
  if constexpr (I < C0) {
    if constexpr (SC0)
      asm volatile("global_load_dwordx4 %0, %1, off offset:%2 sc1"
                   : "=v"(ring[I % DEPTH]) : "v"(b0), "i"(OFF));
    else
      asm volatile("global_load_dwordx4 %0, %1, off offset:%2"
                   : "=v"(ring[I % DEPTH]) : "v"(b0), "i"(OFF));
  } else {
    if constexpr (SC1)
      asm volatile("global_load_dwordx4 %0, %1, off offset:%2 sc1"
                   : "=v"(ring[I % DEPTH]) : "v"(b1), "i"(OFF));
    else
      asm volatile("global_load_dwordx4 %0, %1, off offset:%2"
                   : "=v"(ring[I % DEPTH]) : "v"(b1), "i"(OFF));
  }
}

template <int I, int NPRE, int C0, int DEPTH, bool SC0, bool SC1>
__device__ __forceinline__ void stg_pre(u32x4 (&ring)[DEPTH],
    const u16* b0, const u16* b1) {
  if constexpr (I < NPRE) {
    stg_issue<I, C0, DEPTH, SC0, SC1>(ring, b0, b1);
    stg_pre<I + 1, NPRE, C0, DEPTH, SC0, SC1>(ring, b0, b1);
  }
}

template <int I, int NC, int C0, int DEPTH, bool SC0, bool SC1>
__device__ __forceinline__ void stg_main(u32x4 (&ring)[DEPTH],
    const u16* b0, const u16* b1, u16* lrow) {
  if constexpr (I < NC) {
    constexpr int ISSUED = (I + DEPTH < NC) ? I + DEPTH : NC;
    constexpr int WAIT = ISSUED - I - 1;
    asm volatile("s_waitcnt vmcnt(%1)" : "+v"(ring[I % DEPTH]) : "i"(WAIT));
    *(u32x4*)(lrow + I * 128) = ring[I % DEPTH];   // ds_write_b128 (swizzled)
    if constexpr (I + DEPTH < NC)
      stg_issue<I + DEPTH, C0, DEPTH, SC0, SC1>(ring, b0, b1);
    stg_main<I + 1, NC, C0, DEPTH, SC0, SC1>(ring, b0, b1, lrow);
  }
}

template <int NC, int C0, bool SC0, bool SC1>
__device__ __forceinline__ void stage(const u16* b0, const u16* b1, u16* lrow) {
  u32x4 ring[8];
  stg_pre<0, (NC < 8 ? NC : 8), C0, 8, SC0, SC1>(ring, b0, b1);
  stg_main<0, NC, C0, 8, SC0, SC1>(ring, b0, b1, lrow);
}

// Fence-free tree barrier (R5-proven). bar lines 128B apart: [0]=root,
// [32*(1+g)]=group ctr, [32*(9+g)]=epoch. Monotone counters, no resets.
__device__ __forceinline__ void grid_barrier(unsigned* __restrict__ bar,
                                             int g, unsigned want) {
  asm volatile("s_waitcnt vmcnt(0)" ::: "memory");  // h stores acked at MALL
  __syncthreads();
  if (threadIdx.x == 0) {
    unsigned old = __hip_atomic_fetch_add(bar + 32 * (1 + g), 1u,
                                          __ATOMIC_RELAXED, __HIP_MEMORY_SCOPE_AGENT);
    if (old == 32u * want - 1u) {
      unsigned r = __hip_atomic_fetch_add(bar, 1u, __ATOMIC_RELAXED,
                                          __HIP_MEMORY_SCOPE_AGENT);
      if (r == 8u * want - 1u) {
#pragma unroll
        for (int i = 0; i < 8; ++i)
          __hip_atomic_store(bar + 32 * (9 + i), want, __ATOMIC_RELAXED,
                             __HIP_MEMORY_SCOPE_AGENT);
      }
    }
    while (__hip_atomic_load(bar + 32 * (9 + g), __ATOMIC_RELAXED,
                             __HIP_MEMORY_SCOPE_AGENT) < want)
      __builtin_amdgcn_s_sleep(1);
  }
  __syncthreads();
}

// One layer's persistent loop. Stage chunk = 256 B/row: NC = row_bytes/256.
// MFMA k-chunks NCH = NC*4; wave (cp, kq) = (gate-pair, K-quarter) holds
// breg[2][NC] (gates 2cp,2cp+1; k-chunks kq*NC..kq*NC+NC-1). Each a0/a1
// ds_read feeds 2 MFMAs. A-tile swizzle: elem_off_in_row ^= (row&7)<<3,
// pitch P=K; applied on write (lrow) and per-access on read.
template <int NC, int C0, bool SC0, bool IS2>
__device__ __forceinline__ void run_layer(
    const u16* __restrict__ xbf, const u16* __restrict__ Wt,
    const u16* __restrict__ Ut, const float* __restrict__ bias,
    u16* __restrict__ h1r, u16* __restrict__ h2r, unsigned* __restrict__ bar,
    int strip, int mhalf, char* smem, int g) {
  constexpr int KE = NC * 128;   // K (elements)
  constexpr int P = KE;          // LDS row pitch = K (128B-aligned rows)
  constexpr int WCH = C0 * 4;    // MFMA k-chunks in W segment
  u16* Alds = (u16*)smem;                       // [32][P], swizzled
  float* Zlds = (float*)(smem + LDS_Z_OFF);     // [2][32][68]
  const int tid = threadIdx.x;
  const int wave = tid >> 6, lane = tid & 63;
  const int cp = wave & 1, kq = wave >> 1;      // gate-pair, K-quarter
  const int quad = lane >> 4, l16 = lane & 15;

  // ---- weights -> registers (once; breg[2][NC] -> AGPR-resident) ----
  bf16x8 breg[2][NC];
#pragma unroll
  for (int gi = 0; gi < 2; ++gi) {
    const int col = (2 * cp + gi) * 1024 + strip * 16 + l16;
#pragma unroll
    for (int j = 0; j < NC; ++j) {
      const int ks = kq * NC + j;
      breg[gi][j] = (ks < WCH)
        ? *(const bf16x8*)(Wt + (size_t)col * (C0 * 128) + ks * 32 + quad * 8)
        : *(const bf16x8*)(Ut + (size_t)col * 1024 + (ks - WCH) * 32 + quad * 8);
    }
  }

  // ---- epilogue coords: thread owns one (batch em, unit eu) ----
  const int eu = tid & 15, em = tid >> 4;       // em 0..31
  const float bz0 = bias[strip * 16 + eu];
  const float bz1 = bias[1024 + strip * 16 + eu];
  const float bz2 = bias[2048 + strip * 16 + eu];
  const float bz3 = bias[3072 + strip * 16 + eu];
  float c = 0.f;

  // ---- staging coords: thread stages row sr, 16B slice l8 (16/row) ----
  const int sr = tid >> 4, l8 = tid & 15;
  const int sb = mhalf * 32 + sr;               // global batch row
  // swizzled write base: elem-in-row (l8*8) ^ ((sr&7)<<3); chunk step +I*128
  u16* lrow = Alds + sr * P + ((l8 * 8) ^ ((sr & 7) << 3));

  // swizzled read bases: row l16 (a0) and l16+16 (a1); (row&7) == (l16&7)
  const u16* Arow0 = Alds + l16 * P;
  const u16* Arow1 = Alds + (l16 + 16) * P;
  const int M = (l16 & 7) << 3;                 // element XOR mask (16B slots)

  // Z columns this wave produces: gates 2cp (+0) and 2cp+1 (+16)
  const int zc0 = cp * 32 + l16, zc1 = zc0 + 16;
  float* zb = Zlds + (kq & 1) * (32 * 68);

  for (int s = 0; s <= 256; ++s) {
    const int t = IS2 ? (s - 1) : s;
    if (t >= 0 && t < 256) {
      const u16 *b0, *b1;
      if constexpr (IS2) {
        b0 = h1r + (size_t)(t & 1) * 65536 + (size_t)sb * 1024 + l8 * 8;
        b1 = h2r + (size_t)((t - 1) & 1) * 65536 + (size_t)sb * 1024 + l8 * 8;
      } else {
        b0 = xbf + ((size_t)sb * 256 + t) * 512 + l8 * 8;
        b1 = h1r + (size_t)((t - 1) & 1) * 65536 + (size_t)sb * 1024 + l8 * 8;
      }
      if (t > 0) {
        stage<NC, C0, SC0, true>(b0, b1, lrow);
      } else {                       // first step: recurrent state is zero
        stage<C0, C0, SC0, true>(b0, b0, lrow);
#pragma unroll
        for (int i = C0; i < NC; ++i)
          *(u32x4*)(lrow + i * 128) = (u32x4){0u, 0u, 0u, 0u};
      }
      __syncthreads();

      // acc[gi][mh]: gi = gate-in-pair, mh = m-half (rows mh*16..mh*16+15)
      f32x4 acc00 = {0.f, 0.f, 0.f, 0.f}, acc10 = {0.f, 0.f, 0.f, 0.f};
      f32x4 acc01 = {0.f, 0.f, 0.f, 0.f}, acc11 = {0.f, 0.f, 0.f, 0.f};
#pragma unroll
      for (int j = 0; j < NC; ++j) {
        const int off = (((kq * NC + j) * 32 + quad * 8)) ^ M;  // swizzled
        bf16x8 a0 = *(const bf16x8*)(Arow0 + off);
        bf16x8 a1 = *(const bf16x8*)(Arow1 + off);
        acc00 = __builtin_amdgcn_mfma_f32_16x16x32_bf16(a0, breg[0][j], acc00, 0, 0, 0);
        acc10 = __builtin_amdgcn_mfma_f32_16x16x32_bf16(a1, breg[0][j], acc10, 0, 0, 0);
        acc01 = __builtin_amdgcn_mfma_f32_16x16x32_bf16(a0, breg[1][j], acc01, 0, 0, 0);
        acc11 = __builtin_amdgcn_mfma_f32_16x16x32_bf16(a1, breg[1][j], acc11, 0, 0, 0);
      }

      // kq-partial fold: kq<2 store into buffer (kq&1); sync; kq>=2 add into
      // same buffer; sync. C/D layout: col=lane&15 (unit), row=quad*4+i.
      if (kq < 2) {
#pragma unroll
        for (int i = 0; i < 4; ++i) {
          zb[(quad * 4 + i) * 68 + zc0] = acc00[i];
          zb[(16 + quad * 4 + i) * 68 + zc0] = acc10[i];
          zb[(quad * 4 + i) * 68 + zc1] = acc01[i];
          zb[(16 + quad * 4 + i) * 68 + zc1] = acc11[i];
        }
      }
      __syncthreads();
      if (kq >= 2) {
#pragma unroll
        for (int i = 0; i < 4; ++i) {
          zb[(quad * 4 + i) * 68 + zc0] += acc00[i];
          zb[(16 + quad * 4 + i) * 68 + zc0] += acc10[i];
          zb[(quad * 4 + i) * 68 + zc1] += acc01[i];
          zb[(16 + quad * 4 + i) * 68 + zc1] += acc11[i];
        }
      }
      __syncthreads();

      u16* hring = IS2 ? h2r : h1r;
      u16* hp = hring + (size_t)(t & 1) * 65536 +
                (size_t)(mhalf * 32 + em) * 1024 + strip * 16 + eu;
      {
        float zi = Zlds[em * 68 + eu]      + Zlds[(32 + em) * 68 + eu]      + bz0;
        float zf = Zlds[em * 68 + 16 + eu] + Zlds[(32 + em) * 68 + 16 + eu] + bz1;
        float zg = Zlds[em * 68 + 32 + eu] + Zlds[(32 + em) * 68 + 32 + eu] + bz2;
        float zo = Zlds[em * 68 + 48 + eu] + Zlds[(32 + em) * 68 + 48 + eu] + bz3;
        float ig = 1.f / (1.f + __expf(-zi));
        float fg = 1.f / (1.f + __expf(-zf));
        float gg = 1.f - 2.f / (1.f + __expf(2.f * zg));
        float og = 1.f / (1.f + __expf(-zo));
        c = fg * c + ig * gg;
        float h = og * (1.f - 2.f / (1.f + __expf(2.f * c)));
        store_h_sc1(hp, (unsigned)f2bf(h));
      }
    }
    if (s < 256) grid_barrier(bar, g, (unsigned)(s + 1));
  }
}

__global__ __launch_bounds__(512, 2) void lstm_persistent(
    const u16* __restrict__ xbf,   // [64][256][512] bf16
    const u16* __restrict__ W1t,   // [4096][512]
    const u16* __restrict__ U1t,   // [4096][1024]
    const float* __restrict__ b1,
    const u16* __restrict__ W2t,   // [4096][1024]
    const u16* __restrict__ U2t,   // [4096][1024]
    const float* __restrict__ b2,
    u16* __restrict__ h1r,         // [2][64][1024] bf16
    u16* __restrict__ h2r,         // [2][64][1024] bf16
    unsigned* __restrict__ bar) {
  extern __shared__ __align__(16) char smem[];
  const int blk = blockIdx.x;
  const bool is2 = blk >= 128;
  const int lb = is2 ? blk - 128 : blk;
  const int strip = lb >> 1;       // 64 col-strips of 16 units
  const int mhalf = lb & 1;        // batch half
  const int g = blk & 7;
  if (!is2)
    run_layer<12, 4, false, false>(xbf, W1t, U1t, b1, h1r, h2r, bar,
                                   strip, mhalf, smem, g);
  else
    run_layer<16, 8, true, true>(xbf, W2t, U2t, b2, h1r, h2r, bar,
                                 strip, mhalf, smem, g);
}

// out[64][512] = h2_last @ Wd + bd.  One wave per 16x16 tile, K=1024.
__global__ __launch_bounds__(64) void dense_kernel(
    const u16* __restrict__ h2,    // [64][1024] bf16
    const u16* __restrict__ Wdt,   // [512][1024] bf16
    const float* __restrict__ bd,
    float* __restrict__ out) {
  int mt = blockIdx.x >> 5;  // 0..3
  int nt = blockIdx.x & 31;  // 0..31
  int lane = threadIdx.x;
  int quad = lane >> 4, l16 = lane & 15;
  f32x4 acc = {0.f, 0.f, 0.f, 0.f};
  const u16* ap = h2 + (size_t)(mt * 16 + l16) * 1024 + quad * 8;
  const u16* bp = Wdt + (size_t)(nt * 16 + l16) * 1024 + quad * 8;
#pragma unroll
  for (int ks = 0; ks < 32; ++ks) {
    bf16x8 a = *reinterpret_cast<const bf16x8*>(ap + ks * 32);
    bf16x8 b = *reinterpret_cast<const bf16x8*>(bp + ks * 32);
    acc = __builtin_amdgcn_mfma_f32_16x16x32_bf16(a, b, acc, 0, 0, 0);
  }
  int colo = nt * 16 + l16;
  float bias = bd[colo];
#pragma unroll
  for (int i = 0; i < 4; ++i)
    out[(size_t)(mt * 16 + quad * 4 + i) * 512 + colo] = acc[i] + bias;
}

extern "C" void kernel_launch(void* const* d_in, const int* in_sizes, int n_in,
                              void* d_out, int out_size, void* d_ws, size_t ws_size,
                              hipStream_t stream) {
  const float* x  = (const float*)d_in[0];
  const float* W1 = (const float*)d_in[1];
  const float* U1 = (const float*)d_in[2];
  const float* b1 = (const float*)d_in[3];
  const float* W2 = (const float*)d_in[4];
  const float* U2 = (const float*)d_in[5];
  const float* b2 = (const float*)d_in[6];
  const float* Wd = (const float*)d_in[7];
  const float* bd = (const float*)d_in[8];
  float* out = (float*)d_out;

  char* p = (char*)d_ws;
  auto carve = [&](size_t bytes) -> char* {
    char* r = p;
    p += (bytes + 255) & ~(size_t)255;
    return r;
  };
  // ~45.5 MiB total (R2-proven budget; R1's 78 MiB overflowed ws)
  u16* W1t = (u16*)carve((size_t)4096 * 512 * 2);
  u16* U1t = (u16*)carve((size_t)4096 * 1024 * 2);
  u16* W2t = (u16*)carve((size_t)4096 * 1024 * 2);
  u16* U2t = (u16*)carve((size_t)4096 * 1024 * 2);
  u16* Wdt = (u16*)carve((size_t)512 * 1024 * 2);
  u16* xbf = (u16*)carve((size_t)64 * 256 * 512 * 2);
  u16* h1r = (u16*)carve((size_t)2 * 64 * 1024 * 2);
  u16* h2r = (u16*)carve((size_t)2 * 64 * 1024 * 2);
  unsigned* bar = (unsigned*)carve(1024 * 4);
  (void)ws_size; (void)in_sizes; (void)n_in; (void)out_size;

  transpose_to_bf16<<<dim3(128, 16), 256, 0, stream>>>(W1, W1t, 512, 4096);
  transpose_to_bf16<<<dim3(128, 32), 256, 0, stream>>>(U1, U1t, 1024, 4096);
  transpose_to_bf16<<<dim3(128, 32), 256, 0, stream>>>(W2, W2t, 1024, 4096);
  transpose_to_bf16<<<dim3(128, 32), 256, 0, stream>>>(U2, U2t, 1024, 4096);
  transpose_to_bf16<<<dim3(16, 32), 256, 0, stream>>>(Wd, Wdt, 1024, 512);
  convert_to_bf16<<<8192, 256, 0, stream>>>(x, xbf, 64 * 256 * 512 / 4);
  init_bar<<<1, 1024, 0, stream>>>(bar);

  hipFuncSetAttribute(reinterpret_cast<const void*>(lstm_persistent),
                      hipFuncAttributeMaxDynamicSharedMemorySize, LDS_TOTAL);
  lstm_persistent<<<256, 512, LDS_TOTAL, stream>>>(
      xbf, W1t, U1t, b1, W2t, U2t, b2, h1r, h2r, bar);

  dense_kernel<<<128, 64, 0, stream>>>(h2r + 65536, Wdt, bd, out);
}

// Round 7
// 1476.812 us; speedup vs baseline: 3.4739x; 1.0147x over previous
//
#include <hip/hip_runtime.h>

// ---------------------------------------------------------------------------
// 2-layer LSTM (B=64, T=256, D=512, H1=H2=1024) + dense head.
// R14: decoupled dual-group pipeline. R13 (A-swizzle): bank-conflict counter
// BIT-IDENTICAL to R11 -> conflicts aren't on the A-path; swizzle only added
// VALU addr math (+60us). Reverted to R11 compute. New lever: the 256-block
// grid barrier over-synchronizes -- L1(t) depends only on L1(t-1). Split:
// L1 = blocks 0..127, L2 = 128..255, each with its own 128-block monotone
// tree barrier (R5 pattern, 4 groups x 32). Cross-layer: L1 publishes E1=t+1
// after its barrier; L2 polls E1 >= t+1 before staging h1(t) (cached 'seen'
// amortizes polls); L1 throttles on E2 >= t-7 via an 8-deep h1 ring (1MB) so
// it can't overwrite unconsumed h1. Deadlock-free: L1 at t waits E2>=t-7,
// L2 at u waits E1>=u+1; if both stalled, E1 >= E2+8 > u+1 -> L2 advances.
// L1 (smaller K, fewer bytes) self-paces ahead; critical path = 256 x
// (L2 step + half barrier). Stage/ring/compute/fold byte-identical to R11.
// ---------------------------------------------------------------------------

typedef __bf16 bf16x8 __attribute__((ext_vector_type(8)));
typedef float f32x4 __attribute__((ext_vector_type(4)));
typedef unsigned int u32x4 __attribute__((ext_vector_type(4)));
typedef unsigned short u16;

#define LDS_Z_OFF 131584   // Alds worst: 32*(2048+8)*2 = 131584 B
#define LDS_TOTAL 148992   // + Zlds 2*32*68*4 = 17408 B

__device__ __forceinline__ u16 f2bf(float f) {
  unsigned u = __float_as_uint(f);
  unsigned r = (u + 0x7FFFu + ((u >> 16) & 1u)) >> 16;  // RNE (finite inputs)
  return (u16)r;
}

// in: fp32 [R][C] row-major  ->  out: bf16 [C][R] row-major (i.e. B^T layout)
__global__ __launch_bounds__(256) void transpose_to_bf16(
    const float* __restrict__ in, u16* __restrict__ out, int R, int C) {
  __shared__ float tile[32][33];
  int tx = threadIdx.x & 31, ty = threadIdx.x >> 5;  // 32 x 8
  int c0 = blockIdx.x * 32, r0 = blockIdx.y * 32;
#pragma unroll
  for (int i = 0; i < 4; ++i)
    tile[ty + i * 8][tx] = in[(size_t)(r0 + ty + i * 8) * C + (c0 + tx)];
  __syncthreads();
#pragma unroll
  for (int i = 0; i < 4; ++i)
    out[(size_t)(c0 + ty + i * 8) * R + (r0 + tx)] = f2bf(tile[tx][ty + i * 8]);
}

__global__ __launch_bounds__(256) void convert_to_bf16(
    const float* __restrict__ in, u16* __restrict__ out, int n4) {
  int i = blockIdx.x * 256 + threadIdx.x;
  if (i >= n4) return;
  float4 v = reinterpret_cast<const float4*>(in)[i];
  ushort4 o;
  o.x = f2bf(v.x); o.y = f2bf(v.y); o.z = f2bf(v.z); o.w = f2bf(v.w);
  reinterpret_cast<ushort4*>(out)[i] = o;
}

__global__ void init_bar(unsigned* __restrict__ bar) {
  bar[blockIdx.x * 1024 + threadIdx.x] = 0u;
}

__device__ __forceinline__ void store_h_sc1(u16* p, unsigned v) {
  asm volatile("global_store_short %0, %1, off sc1" :: "v"(p), "v"(v) : "memory");
}

// ---- A-staging: sc1/cached loads -> LDS via depth-8 ring, manual vmcnt ----
// Chunk = 32 rows x 256 B (one 16B slice per thread, 512 threads).
template <int I, int C0, int DEPTH, bool SC0, bool SC1>
__device__ __forceinline__ void stg_issue(u32x4 (&ring)[DEPTH],
    const u16* b0, const u16* b1) {
  constexpr int OFF = (I < C0 ? I : I - C0) * 256;
  if constexpr (I < C0) {
    if constexpr (SC0)
      asm volatile("global_load_dwordx4 %0, %1, off offset:%2 sc1"
                   : "=v"(ring[I % DEPTH]) : "v"(b0), "i"(OFF));
    else
      asm volatile("global_load_dwordx4 %0, %1, off offset:%2"
                   : "=v"(ring[I % DEPTH]) : "v"(b0), "i"(OFF));
  } else {
    if constexpr (SC1)
      asm volatile("global_load_dwordx4 %0, %1, off offset:%2 sc1"
                   : "=v"(ring[I % DEPTH]) : "v"(b1), "i"(OFF));
    else
      asm volatile("global_load_dwordx4 %0, %1, off offset:%2"
                   : "=v"(ring[I % DEPTH]) : "v"(b1), "i"(OFF));
  }
}

template <int I, int NPRE, int C0, int DEPTH, bool SC0, bool SC1>
__device__ __forceinline__ void stg_pre(u32x4 (&ring)[DEPTH],
    const u16* b0, const u16* b1) {
  if constexpr (I < NPRE) {
    stg_issue<I, C0, DEPTH, SC0, SC1>(ring, b0, b1);
    stg_pre<I + 1, NPRE, C0, DEPTH, SC0, SC1>(ring, b0, b1);
  }
}

template <int I, int NC, int C0, int DEPTH, bool SC0, bool SC1>
__device__ __forceinline__ void stg_main(u32x4 (&ring)[DEPTH],
    const u16* b0, const u16* b1, u16* lrow) {
  if constexpr (I < NC) {
    constexpr int ISSUED = (I + DEPTH < NC) ? I + DEPTH : NC;
    constexpr int WAIT = ISSUED - I - 1;
    asm volatile("s_waitcnt vmcnt(%1)" : "+v"(ring[I % DEPTH]) : "i"(WAIT));
    *(u32x4*)(lrow + I * 128) = ring[I % DEPTH];   // ds_write_b128
    if constexpr (I + DEPTH < NC)
      stg_issue<I + DEPTH, C0, DEPTH, SC0, SC1>(ring, b0, b1);
    stg_main<I + 1, NC, C0, DEPTH, SC0, SC1>(ring, b0, b1, lrow);
  }
}

template <int NC, int C0, bool SC0, bool SC1>
__device__ __forceinline__ void stage(const u16* b0, const u16* b1, u16* lrow) {
  u32x4 ring[8];
  stg_pre<0, (NC < 8 ? NC : 8), C0, 8, SC0, SC1>(ring, b0, b1);
  stg_main<0, NC, C0, 8, SC0, SC1>(ring, b0, b1, lrow);
}

// 128-block tree barrier (R5 pattern, 4 groups x 32, monotone, no resets).
// ubar layout (u32 idx): [0]=root, [32*(1+g)]=group ctr, [32*(9+g)]=epoch.
// Root winner also publishes this layer's cross epoch (epub = want).
__device__ __forceinline__ void group_barrier(unsigned* __restrict__ ubar,
                                              unsigned* __restrict__ epub,
                                              int g, unsigned want) {
  asm volatile("s_waitcnt vmcnt(0)" ::: "memory");  // h stores acked at MALL
  __syncthreads();
  if (threadIdx.x == 0) {
    unsigned old = __hip_atomic_fetch_add(ubar + 32 * (1 + g), 1u,
                                          __ATOMIC_RELAXED, __HIP_MEMORY_SCOPE_AGENT);
    if (old == 32u * want - 1u) {
      unsigned r = __hip_atomic_fetch_add(ubar, 1u, __ATOMIC_RELAXED,
                                          __HIP_MEMORY_SCOPE_AGENT);
      if (r == 4u * want - 1u) {
        __hip_atomic_store(epub, want, __ATOMIC_RELAXED,
                           __HIP_MEMORY_SCOPE_AGENT);
#pragma unroll
        for (int i = 0; i < 4; ++i)
          __hip_atomic_store(ubar + 32 * (9 + i), want, __ATOMIC_RELAXED,
                             __HIP_MEMORY_SCOPE_AGENT);
      }
    }
    while (__hip_atomic_load(ubar + 32 * (9 + g), __ATOMIC_RELAXED,
                             __HIP_MEMORY_SCOPE_AGENT) < want)
      __builtin_amdgcn_s_sleep(1);
  }
  __syncthreads();
}

// Wait until *p >= v (thread0 polls, cached 'seen' skips redundant loads).
__device__ __forceinline__ void wait_epoch(unsigned* __restrict__ p,
                                           unsigned v, unsigned& seen) {
  if (threadIdx.x == 0) {
    while (seen < v) {
      seen = __hip_atomic_load(p, __ATOMIC_RELAXED, __HIP_MEMORY_SCOPE_AGENT);
      if (seen < v) __builtin_amdgcn_s_sleep(2);
    }
  }
  __syncthreads();
}

// One layer's persistent loop (own 128-block barrier + cross epochs).
// Stage chunk = 256 B/row: NC = row_bytes/256. Wave (cp, kq) = (gate-pair,
// K-quarter) holds breg[2][NC]; each a0/a1 ds_read feeds 2 MFMAs (R11).
// L1 (!IS2): b0 = x(t) cached, b1 = h1(t-1) sc1; writes h1 slot t&7 (8-ring).
// L2 (IS2): waits E1>=t+1; b0 = h1(t) sc1, b1 = h2(t-1) sc1; writes h2 t&1.
// L1 ring guard: waits E2 >= t-7 before overwriting h1 slot t&7.
template <int NC, int C0, bool SC0, bool IS2>
__device__ __forceinline__ void run_layer(
    const u16* __restrict__ xbf, const u16* __restrict__ Wt,
    const u16* __restrict__ Ut, const float* __restrict__ bias,
    u16* __restrict__ h1r, u16* __restrict__ h2r,
    unsigned* __restrict__ ubar, unsigned* __restrict__ epub,
    unsigned* __restrict__ ewait,
    int strip, int mhalf, char* smem, int g) {
  constexpr int KE = NC * 128;   // K (elements)
  constexpr int P = KE + 8;      // LDS row pitch (elements); +16B bank stagger
  constexpr int WCH = C0 * 4;    // MFMA k-chunks in W segment
  u16* Alds = (u16*)smem;                       // [32][P]
  float* Zlds = (float*)(smem + LDS_Z_OFF);     // [2][32][68]
  const int tid = threadIdx.x;
  const int wave = tid >> 6, lane = tid & 63;
  const int cp = wave & 1, kq = wave >> 1;      // gate-pair, K-quarter
  const int quad = lane >> 4, l16 = lane & 15;

  // ---- weights -> registers (once; breg[2][NC] -> AGPR-resident) ----
  bf16x8 breg[2][NC];
#pragma unroll
  for (int gi = 0; gi < 2; ++gi) {
    const int col = (2 * cp + gi) * 1024 + strip * 16 + l16;
#pragma unroll
    for (int j = 0; j < NC; ++j) {
      const int ks = kq * NC + j;
      breg[gi][j] = (ks < WCH)
        ? *(const bf16x8*)(Wt + (size_t)col * (C0 * 128) + ks * 32 + quad * 8)
        : *(const bf16x8*)(Ut + (size_t)col * 1024 + (ks - WCH) * 32 + quad * 8);
    }
  }

  // ---- epilogue coords: thread owns one (batch em, unit eu) ----
  const int eu = tid & 15, em = tid >> 4;       // em 0..31
  const float bz0 = bias[strip * 16 + eu];
  const float bz1 = bias[1024 + strip * 16 + eu];
  const float bz2 = bias[2048 + strip * 16 + eu];
  const float bz3 = bias[3072 + strip * 16 + eu];
  float c = 0.f;

  // ---- staging coords: thread stages row sr, 16B slice l8 (16/row) ----
  const int sr = tid >> 4, l8 = tid & 15;
  const int sb = mhalf * 32 + sr;               // global batch row
  u16* lrow = Alds + sr * P + l8 * 8;

  const u16* a0p = Alds + l16 * P + quad * 8 + kq * (NC * 32);
  const u16* a1p = a0p + 16 * P;

  // Z columns this wave produces: gates 2cp (+0) and 2cp+1 (+16)
  const int zc0 = cp * 32 + l16, zc1 = zc0 + 16;
  float* zb = Zlds + (kq & 1) * (32 * 68);

  unsigned eseen = 0;                           // thread-0 epoch cache

  for (int t = 0; t < 256; ++t) {
    // ---- cross-layer gating ----
    if constexpr (IS2) {
      wait_epoch(ewait, (unsigned)(t + 1), eseen);       // h1(t) published
    } else {
      if (t >= 8) wait_epoch(ewait, (unsigned)(t - 7), eseen);  // ring free
    }

    const u16 *b0, *b1;
    if constexpr (IS2) {
      b0 = h1r + (size_t)(t & 7) * 65536 + (size_t)sb * 1024 + l8 * 8;
      b1 = h2r + (size_t)((t - 1) & 1) * 65536 + (size_t)sb * 1024 + l8 * 8;
    } else {
      b0 = xbf + ((size_t)sb * 256 + t) * 512 + l8 * 8;
      b1 = h1r + (size_t)((t - 1) & 7) * 65536 + (size_t)sb * 1024 + l8 * 8;
    }
    if (t > 0) {
      stage<NC, C0, SC0, true>(b0, b1, lrow);
    } else {                       // first step: recurrent state is zero
      stage<C0, C0, SC0, true>(b0, b0, lrow);
#pragma unroll
      for (int i = C0; i < NC; ++i)
        *(u32x4*)(lrow + i * 128) = (u32x4){0u, 0u, 0u, 0u};
    }
    __syncthreads();

    // acc[gi][mh]: gi = gate-in-pair, mh = m-half (rows mh*16..mh*16+15)
    f32x4 acc00 = {0.f, 0.f, 0.f, 0.f}, acc10 = {0.f, 0.f, 0.f, 0.f};
    f32x4 acc01 = {0.f, 0.f, 0.f, 0.f}, acc11 = {0.f, 0.f, 0.f, 0.f};
#pragma unroll
    for (int j = 0; j < NC; ++j) {
      bf16x8 a0 = *(const bf16x8*)(a0p + j * 32);
      bf16x8 a1 = *(const bf16x8*)(a1p + j * 32);
      acc00 = __builtin_amdgcn_mfma_f32_16x16x32_bf16(a0, breg[0][j], acc00, 0, 0, 0);
      acc10 = __builtin_amdgcn_mfma_f32_16x16x32_bf16(a1, breg[0][j], acc10, 0, 0, 0);
      acc01 = __builtin_amdgcn_mfma_f32_16x16x32_bf16(a0, breg[1][j], acc01, 0, 0, 0);
      acc11 = __builtin_amdgcn_mfma_f32_16x16x32_bf16(a1, breg[1][j], acc11, 0, 0, 0);
    }

    // kq-partial fold: kq<2 store into buffer (kq&1); sync; kq>=2 add into
    // same buffer; sync. C/D layout: col=lane&15 (unit), row=quad*4+i.
    if (kq < 2) {
#pragma unroll
      for (int i = 0; i < 4; ++i) {
        zb[(quad * 4 + i) * 68 + zc0] = acc00[i];
        zb[(16 + quad * 4 + i) * 68 + zc0] = acc10[i];
        zb[(quad * 4 + i) * 68 + zc1] = acc01[i];
        zb[(16 + quad * 4 + i) * 68 + zc1] = acc11[i];
      }
    }
    __syncthreads();
    if (kq >= 2) {
#pragma unroll
      for (int i = 0; i < 4; ++i) {
        zb[(quad * 4 + i) * 68 + zc0] += acc00[i];
        zb[(16 + quad * 4 + i) * 68 + zc0] += acc10[i];
        zb[(quad * 4 + i) * 68 + zc1] += acc01[i];
        zb[(16 + quad * 4 + i) * 68 + zc1] += acc11[i];
      }
    }
    __syncthreads();

    u16* hp = IS2
      ? h2r + (size_t)(t & 1) * 65536 + (size_t)(mhalf * 32 + em) * 1024 + strip * 16 + eu
      : h1r + (size_t)(t & 7) * 65536 + (size_t)(mhalf * 32 + em) * 1024 + strip * 16 + eu;
    {
      float zi = Zlds[em * 68 + eu]      + Zlds[(32 + em) * 68 + eu]      + bz0;
      float zf = Zlds[em * 68 + 16 + eu] + Zlds[(32 + em) * 68 + 16 + eu] + bz1;
      float zg = Zlds[em * 68 + 32 + eu] + Zlds[(32 + em) * 68 + 32 + eu] + bz2;
      float zo = Zlds[em * 68 + 48 + eu] + Zlds[(32 + em) * 68 + 48 + eu] + bz3;
      float ig = 1.f / (1.f + __expf(-zi));
      float fg = 1.f / (1.f + __expf(-zf));
      float gg = 1.f - 2.f / (1.f + __expf(2.f * zg));
      float og = 1.f / (1.f + __expf(-zo));
      c = fg * c + ig * gg;
      float h = og * (1.f - 2.f / (1.f + __expf(2.f * c)));
      store_h_sc1(hp, (unsigned)f2bf(h));
    }

    group_barrier(ubar, epub, g, (unsigned)(t + 1));
  }
}

__global__ __launch_bounds__(512, 2) void lstm_persistent(
    const u16* __restrict__ xbf,   // [64][256][512] bf16
    const u16* __restrict__ W1t,   // [4096][512]
    const u16* __restrict__ U1t,   // [4096][1024]
    const float* __restrict__ b1,
    const u16* __restrict__ W2t,   // [4096][1024]
    const u16* __restrict__ U2t,   // [4096][1024]
    const float* __restrict__ b2,
    u16* __restrict__ h1r,         // [8][64][1024] bf16 ring
    u16* __restrict__ h2r,         // [2][64][1024] bf16 ring
    unsigned* __restrict__ bar) {  // [2][2048] u32: per-layer barrier regions
  extern __shared__ __align__(16) char smem[];
  const int blk = blockIdx.x;
  const bool is2 = blk >= 128;
  const int lb = is2 ? blk - 128 : blk;
  const int strip = lb >> 1;       // 64 col-strips of 16 units
  const int mhalf = lb & 1;        // batch half
  const int g = lb & 3;            // 4 tree-groups of 32 blocks
  unsigned* ubar  = bar + (is2 ? 2048 : 0);
  unsigned* epub  = ubar + 512;                    // this layer's epoch
  unsigned* ewait = (is2 ? bar : bar + 2048) + 512;  // other layer's epoch
  if (!is2)
    run_layer<12, 4, false, false>(xbf, W1t, U1t, b1, h1r, h2r,
                                   ubar, epub, ewait, strip, mhalf, smem, g);
  else
    run_layer<16, 8, true, true>(xbf, W2t, U2t, b2, h1r, h2r,
                                 ubar, epub, ewait, strip, mhalf, smem, g);
}

// out[64][512] = h2_last @ Wd + bd.  One wave per 16x16 tile, K=1024.
__global__ __launch_bounds__(64) void dense_kernel(
    const u16* __restrict__ h2,    // [64][1024] bf16
    const u16* __restrict__ Wdt,   // [512][1024] bf16
    const float* __restrict__ bd,
    float* __restrict__ out) {
  int mt = blockIdx.x >> 5;  // 0..3
  int nt = blockIdx.x & 31;  // 0..31
  int lane = threadIdx.x;
  int quad = lane >> 4, l16 = lane & 15;
  f32x4 acc = {0.f, 0.f, 0.f, 0.f};
  const u16* ap = h2 + (size_t)(mt * 16 + l16) * 1024 + quad * 8;
  const u16* bp = Wdt + (size_t)(nt * 16 + l16) * 1024 + quad * 8;
#pragma unroll
  for (int ks = 0; ks < 32; ++ks) {
    bf16x8 a = *reinterpret_cast<const bf16x8*>(ap + ks * 32);
    bf16x8 b = *reinterpret_cast<const bf16x8*>(bp + ks * 32);
    acc = __builtin_amdgcn_mfma_f32_16x16x32_bf16(a, b, acc, 0, 0, 0);
  }
  int colo = nt * 16 + l16;
  float bias = bd[colo];
#pragma unroll
  for (int i = 0; i < 4; ++i)
    out[(size_t)(mt * 16 + quad * 4 + i) * 512 + colo] = acc[i] + bias;
}

extern "C" void kernel_launch(void* const* d_in, const int* in_sizes, int n_in,
                              void* d_out, int out_size, void* d_ws, size_t ws_size,
                              hipStream_t stream) {
  const float* x  = (const float*)d_in[0];
  const float* W1 = (const float*)d_in[1];
  const float* U1 = (const float*)d_in[2];
  const float* b1 = (const float*)d_in[3];
  const float* W2 = (const float*)d_in[4];
  const float* U2 = (const float*)d_in[5];
  const float* b2 = (const float*)d_in[6];
  const float* Wd = (const float*)d_in[7];
  const float* bd = (const float*)d_in[8];
  float* out = (float*)d_out;

  char* p = (char*)d_ws;
  auto carve = [&](size_t bytes) -> char* {
    char* r = p;
    p += (bytes + 255) & ~(size_t)255;
    return r;
  };
  // ~46.3 MiB total (R2-proven ~45.5 budget + 0.8 MiB h1 ring; R1's 78 MiB
  // overflowed -> still well inside)
  u16* W1t = (u16*)carve((size_t)4096 * 512 * 2);
  u16* U1t = (u16*)carve((size_t)4096 * 1024 * 2);
  u16* W2t = (u16*)carve((size_t)4096 * 1024 * 2);
  u16* U2t = (u16*)carve((size_t)4096 * 1024 * 2);
  u16* Wdt = (u16*)carve((size_t)512 * 1024 * 2);
  u16* xbf = (u16*)carve((size_t)64 * 256 * 512 * 2);
  u16* h1r = (u16*)carve((size_t)8 * 64 * 1024 * 2);   // 8-deep ring
  u16* h2r = (u16*)carve((size_t)2 * 64 * 1024 * 2);
  unsigned* bar = (unsigned*)carve(4096 * 4);          // 2 x 2048 u32 regions
  (void)ws_size; (void)in_sizes; (void)n_in; (void)out_size;

  transpose_to_bf16<<<dim3(128, 16), 256, 0, stream>>>(W1, W1t, 512, 4096);
  transpose_to_bf16<<<dim3(128, 32), 256, 0, stream>>>(U1, U1t, 1024, 4096);
  transpose_to_bf16<<<dim3(128, 32), 256, 0, stream>>>(W2, W2t, 1024, 4096);
  transpose_to_bf16<<<dim3(128, 32), 256, 0, stream>>>(U2, U2t, 1024, 4096);
  transpose_to_bf16<<<dim3(16, 32), 256, 0, stream>>>(Wd, Wdt, 1024, 512);
  convert_to_bf16<<<8192, 256, 0, stream>>>(x, xbf, 64 * 256 * 512 / 4);
  init_bar<<<4, 1024, 0, stream>>>(bar);

  hipFuncSetAttribute(reinterpret_cast<const void*>(lstm_persistent),
                      hipFuncAttributeMaxDynamicSharedMemorySize, LDS_TOTAL);
  lstm_persistent<<<256, 512, LDS_TOTAL, stream>>>(
      xbf, W1t, U1t, b1, W2t, U2t, b2, h1r, h2r, bar);

  dense_kernel<<<128, 64, 0, stream>>>(h2r + 65536, Wdt, bd, out);
}